// Round 10
// baseline (355.756 us; speedup 1.0000x reference)
//
#include <hip/hip_runtime.h>
#include <math.h>

typedef __attribute__((ext_vector_type(8))) short short8;
typedef __attribute__((ext_vector_type(4))) float f32x4;
typedef unsigned short u16;

__device__ __forceinline__ float b2f(u16 u) {
    union { unsigned u; float f; } c; c.u = ((unsigned)u) << 16; return c.f;
}
__device__ __forceinline__ u16 f2b(float f) {
    unsigned u = __float_as_uint(f);
    u += 0x7fffu + ((u >> 16) & 1u);   // RNE
    return (u16)(u >> 16);
}

__device__ __forceinline__ void gl_lds16(const u16* g, u16* l) {
    __builtin_amdgcn_global_load_lds(
        (const __attribute__((address_space(1))) void*)g,
        (__attribute__((address_space(3))) void*)l,
        16, 0, 0);
}

// XCD-chunked 2D block swizzle (T1): work id = (l%8)*(nxy/8) + l/8 gives
// each XCD a contiguous chunk of (x,y) tiles (A-panel fetched once per XCD
// instead of 8x). Verified R9: dual FETCH 135.7 -> 90.3 MB. Bijective:
// nxy % 8 == 0 for all launches here. R8 lesson: never combine with a
// logical-coordinate early-exit (concentrates exits onto a subset of XCDs).
__device__ __forceinline__ void xcd_swz(int& bx, int& by) {
    const int nxy = gridDim.x * gridDim.y;
    const int l = blockIdx.x + gridDim.x * blockIdx.y;
    const int l2 = (l & 7) * (nxy >> 3) + (l >> 3);
    bx = l2 % gridDim.x;
    by = l2 / gridDim.x;
}

// fused fp32 -> bf16 conversion: x (blocks 0..4095) + 4 weight matrices
// (blocks 4096..6143) + two-level RoPE tables (blocks 6144..6239).
// ang(pos,f) = hi*64*th_f + lo*th_f; T1[512][32] + T2[512][64] = 384 KB,
// L2-resident (R6 lesson: an 8 MB table thrashes the 4 MB per-XCD L2).
// Trig lives HERE, in a low-register-pressure kernel (R5 lesson: libm in
// a GEMM epilogue spills to scratch). Composition verified in R7 (absmax
// identical to direct sincosf).
__global__ __launch_bounds__(256) void cvt_all(
    const float* __restrict__ x,
    const float* __restrict__ w0, const float* __restrict__ w1,
    const float* __restrict__ w2, const float* __restrict__ w3,
    u16* __restrict__ xb, u16* __restrict__ wb,
    float* __restrict__ ct1, float* __restrict__ st1,
    float* __restrict__ ct2, float* __restrict__ st2)
{
    const int b = blockIdx.x;
    if (b >= 6144) {
        const int j = b - 6144;            // 0..95
#pragma unroll
        for (int it = 0; it < 2; ++it) {
            const int f = threadIdx.x + it * 256;   // 0..511
            const float inv = powf(10000.0f, -(float)f * (1.0f / 512.0f));
            float sn, cs;
            if (j < 32) {                  // T1: pos_hi = j
                sincosf((float)(j * 64) * inv, &sn, &cs);
                ct1[f * 32 + j] = cs;
                st1[f * 32 + j] = sn;
            } else {                       // T2: pos_lo = j-32
                const int lo = j - 32;
                sincosf((float)lo * inv, &sn, &cs);
                ct2[f * 64 + lo] = cs;
                st2[f * 64 + lo] = sn;
            }
        }
        return;
    }
    const float* src; u16* dst; int i;
    if (b < 4096) {
        i = (b * 256 + threadIdx.x) * 8;
        src = x; dst = xb;
    } else {
        const int j = b - 4096;
        const int z = j >> 9;
        src = (z == 0) ? w0 : (z == 1) ? w1 : (z == 2) ? w2 : w3;
        i = ((j & 511) * 256 + threadIdx.x) * 8;
        dst = wb + (long)z * 1024 * 1024;
    }
    const float4 a = *(const float4*)&src[i];
    const float4 c = *(const float4*)&src[i + 4];
    short8 o;
    o[0] = (short)f2b(a.x); o[1] = (short)f2b(a.y);
    o[2] = (short)f2b(a.z); o[3] = (short)f2b(a.w);
    o[4] = (short)f2b(c.x); o[5] = (short)f2b(c.y);
    o[6] = (short)f2b(c.z); o[7] = (short)f2b(c.w);
    *(short8*)&dst[i] = o;
}

// Shared 128x128-tile GEMM body: C[M,N] = scale * A[M,K] @ W[N,K]^T
// bf16 in, fp32 accum. XOR-swizzled LDS (0 conflicts, verified R0);
// loop-carried pointers; double-buffered glds K-loop, ONE barrier per step.
// R0-proven structure (697 TF here — best of 5 schedule variants R1-R4).
template<typename OT>
__device__ __forceinline__ void gemm_body(
    const u16* __restrict__ A, const u16* __restrict__ W, OT* __restrict__ C,
    int lda, int ldw, int ldc, int K, float scale, int bx, int by)
{
    __shared__ u16 lsA[2][128 * 32];
    __shared__ u16 lsB[2][128 * 32];

    const int m0 = by * 128;
    const int n0 = bx * 128;
    const int t = threadIdx.x;
    const int lane = t & 63;
    const int wave = t >> 6;
    const int wm = (wave & 1) * 64;
    const int wn = (wave >> 1) * 64;

    // staging: thread t covers row sr; col-group XOR-swizzled by (t>>3)&3
    const int sr = t >> 2;
    const int scol = ((t & 3) ^ ((t >> 3) & 3)) * 8;

    // loop-carried global pointers (advance 32 elems = 64 B per K-step)
    const u16* pa0 = A + (long)(m0 + sr) * lda + scol;
    const u16* pa1 = pa0 + (long)64 * lda;
    const u16* pw0 = W + (long)(n0 + sr) * ldw + scol;
    const u16* pw1 = pw0 + (long)64 * ldw;

    f32x4 acc[4][4];
#pragma unroll
    for (int i = 0; i < 4; ++i)
#pragma unroll
        for (int j = 0; j < 4; ++j)
            acc[i][j] = (f32x4){0.f, 0.f, 0.f, 0.f};

    const int fr = lane & 15;   // fragment row (m / n)
    const int fq = lane >> 4;   // quad
    const int swz = (fq ^ ((fr >> 1) & 3)) * 8;
    const int aoff = (wm + fr) * 32 + swz;
    const int boff = (wn + fr) * 32 + swz;

    // prologue: tile 0 -> buffer 0
    gl_lds16(pa0, &lsA[0][t * 8]);        pa0 += 32;
    gl_lds16(pa1, &lsA[0][2048 + t * 8]); pa1 += 32;
    gl_lds16(pw0, &lsB[0][t * 8]);        pw0 += 32;
    gl_lds16(pw1, &lsB[0][2048 + t * 8]); pw1 += 32;

    const int nsteps = K >> 5;
    int par = 0;
    for (int s = 0; s < nsteps; ++s) {
        __syncthreads();   // drains vmcnt: buf[par] ready; prior ds_reads done
        if (s + 1 < nsteps) {
            const int np = par ^ 1;
            gl_lds16(pa0, &lsA[np][t * 8]);        pa0 += 32;
            gl_lds16(pa1, &lsA[np][2048 + t * 8]); pa1 += 32;
            gl_lds16(pw0, &lsB[np][t * 8]);        pw0 += 32;
            gl_lds16(pw1, &lsB[np][2048 + t * 8]); pw1 += 32;
        }

        short8 af[4], bf[4];
#pragma unroll
        for (int i = 0; i < 4; ++i)
            af[i] = *(const short8*)&lsA[par][aoff + i * 512];
#pragma unroll
        for (int j = 0; j < 4; ++j)
            bf[j] = *(const short8*)&lsB[par][boff + j * 512];
#pragma unroll
        for (int i = 0; i < 4; ++i)
#pragma unroll
            for (int j = 0; j < 4; ++j)
                acc[i][j] = __builtin_amdgcn_mfma_f32_16x16x32_bf16(af[i], bf[j], acc[i][j], 0, 0, 0);
        par ^= 1;
    }

    // C/D layout: col = lane&15, row = quad*4 + reg  [verified m89/m91]
#pragma unroll
    for (int i = 0; i < 4; ++i) {
#pragma unroll
        for (int j = 0; j < 4; ++j) {
            const int row0 = m0 + wm + i * 16 + fq * 4;
            const int col = n0 + wn + j * 16 + fr;
#pragma unroll
            for (int r = 0; r < 4; ++r) {
                const int row = row0 + r;
                const float val = acc[i][j][r] * scale;
                if (sizeof(OT) == 2) {
                    ((u16*)C)[(long)row * ldc + col] = f2b(val);
                } else {
                    ((float*)C)[(long)row * ldc + col] = val;
                }
            }
        }
    }
}

// generic z-strided GEMM (XCD-swizzled tiles; no early exits here)
template<typename OT>
__global__ __launch_bounds__(256) void gemm_bt(
    const u16* __restrict__ A, const u16* __restrict__ W, OT* __restrict__ C,
    int lda, int ldw, int ldc, int K,
    long sA, long sW, long sC, float scale)
{
    int bx, by;
    xcd_swz(bx, by);
    const int bz = blockIdx.z;
    gemm_body<OT>(A + (long)bz * sA, W + (long)bz * sW, C + (long)bz * sC,
                  lda, ldw, ldc, K, scale, bx, by);
}

// Fused dispatch: blocks 0..511 = UT GEMM (UT[b] = wo @ v[b]^T, M=1024,
// N=2048, K=1024; raw coords, exact block count), blocks 512..8703 = RoPE
// on q AND k (one block per row; table-driven — no powf/sincosf; 8 B
// vectorized accesses). UT depends only on v/wo, so it overlaps rope's
// memory-bound phase instead of serializing after it (was inside dual).
__global__ __launch_bounds__(256) void rope_ut(
    u16* __restrict__ q, u16* __restrict__ k,
    const float* __restrict__ ct1, const float* __restrict__ st1,
    const float* __restrict__ ct2, const float* __restrict__ st2,
    const u16* __restrict__ wob, const u16* __restrict__ v, u16* __restrict__ UT)
{
    const long M1 = 1024 * 1024;
    const int b = blockIdx.x;
    if (b < 512) {           // UT: batch = b>>7, x = b&15, y = (b>>4)&7
        const int batch = b >> 7;
        const int bx = b & 15;
        const int by = (b >> 4) & 7;
        gemm_body<u16>(wob, v + (long)batch * 2 * M1, UT + (long)batch * 2 * M1,
                       1024, 1024, 2048, 1024, 1.0f, bx, by);
        return;
    }
    const int row = b - 512;           // 0..8191
    const int pos = row & 2047;
    const int hi = pos >> 6;
    const int lo = pos & 63;
    const int t = threadIdx.x;
    const int f0 = 2 * t;              // pairs f0, f0+1 -> elems 4t..4t+3

    const float c1a = ct1[f0 * 32 + hi],       s1a = st1[f0 * 32 + hi];
    const float c2a = ct2[f0 * 64 + lo],       s2a = st2[f0 * 64 + lo];
    const float c1b = ct1[(f0 + 1) * 32 + hi], s1b = st1[(f0 + 1) * 32 + hi];
    const float c2b = ct2[(f0 + 1) * 64 + lo], s2b = st2[(f0 + 1) * 64 + lo];
    const float ca = c1a * c2a - s1a * s2a, sa = s1a * c2a + c1a * s2a;
    const float cb = c1b * c2b - s1b * s2b, sb = s1b * c2b + c1b * s2b;

    u16* pq = q + (long)row * 1024 + 4 * t;
    u16* pk = k + (long)row * 1024 + 4 * t;

    ushort4 vq = *(ushort4*)pq;
    {
        const float xr0 = b2f(vq.x), xi0 = b2f(vq.y);
        const float xr1 = b2f(vq.z), xi1 = b2f(vq.w);
        vq.x = f2b(xr0 * ca - xi0 * sa); vq.y = f2b(xr0 * sa + xi0 * ca);
        vq.z = f2b(xr1 * cb - xi1 * sb); vq.w = f2b(xr1 * sb + xi1 * cb);
    }
    *(ushort4*)pq = vq;

    ushort4 vk = *(ushort4*)pk;
    {
        const float xr0 = b2f(vk.x), xi0 = b2f(vk.y);
        const float xr1 = b2f(vk.z), xi1 = b2f(vk.w);
        vk.x = f2b(xr0 * ca - xi0 * sa); vk.y = f2b(xr0 * sa + xi0 * ca);
        vk.z = f2b(xr1 * cb - xi1 * sb); vk.w = f2b(xr1 * sb + xi1 * cb);
    }
    *(ushort4*)pk = vk;
}

// row-wise softmax over 2048 bf16 entries, in-place safe; one block per row
__global__ __launch_bounds__(256) void softmax_kernel(const u16* __restrict__ S, u16* __restrict__ P) {
    const long row = blockIdx.x;
    const u16* src = S + row * 2048;
    u16* dst = P + row * 2048;
    const int t = threadIdx.x;
    const int lane = t & 63;
    const int wave = t >> 6;
    __shared__ float red[4];

    float v[8];
    const short8 raw = *(const short8*)&src[t * 8];
#pragma unroll
    for (int i = 0; i < 8; ++i) v[i] = b2f((u16)raw[i]);

    float m = v[0];
#pragma unroll
    for (int i = 1; i < 8; ++i) m = fmaxf(m, v[i]);
    for (int o = 32; o > 0; o >>= 1) m = fmaxf(m, __shfl_xor(m, o, 64));
    if (lane == 0) red[wave] = m;
    __syncthreads();
    m = fmaxf(fmaxf(red[0], red[1]), fmaxf(red[2], red[3]));
    __syncthreads();

    float sum = 0.f;
#pragma unroll
    for (int i = 0; i < 8; ++i) { v[i] = expf(v[i] - m); sum += v[i]; }
    for (int o = 32; o > 0; o >>= 1) sum += __shfl_xor(sum, o, 64);
    if (lane == 0) red[wave] = sum;
    __syncthreads();
    sum = red[0] + red[1] + red[2] + red[3];
    const float is = 1.0f / sum;

    short8 outv;
#pragma unroll
    for (int i = 0; i < 8; ++i) outv[i] = (short)f2b(v[i] * is);
    *(short8*)&dst[t * 8] = outv;
}

extern "C" void kernel_launch(void* const* d_in, const int* in_sizes, int n_in,
                              void* d_out, int out_size, void* d_ws, size_t ws_size,
                              hipStream_t stream)
{
    (void)in_sizes; (void)n_in; (void)out_size; (void)ws_size;
    const float* x  = (const float*)d_in[0];
    const float* wq = (const float*)d_in[1];
    const float* wk = (const float*)d_in[2];
    const float* wv = (const float*)d_in[3];
    const float* wo = (const float*)d_in[4];
    float* out = (float*)d_out;

    // workspace layout (bf16 elements), 104 MB + 384 KB tables
    // (ws_size >= 112 MB verified on this harness: R6/R7 ran an 8 MB table)
    const long M1 = 1024 * 1024;
    u16* ws  = (u16*)d_ws;
    u16* xb  = ws;               // [8192][1024] bf16 x; reused as UT after QKV
    u16* wqb = xb + 8 * M1;      // [4][1024][1024] wq,wk,wv,wo contiguous
    u16* wob = wqb + 3 * M1;
    u16* q   = wqb + 4 * M1;     // [8192][1024]; kk, v contiguous after (z-strided)
    u16* kk  = q + 8 * M1;
    u16* v   = kk + 8 * M1;
    u16* sc  = v + 8 * M1;       // [4][2048][2048], softmax in-place
    u16* UT  = xb;               // alias: [4][1024][2048], xb dead after QKV
    float* ct1 = (float*)(sc + 16 * M1);  // [512 f][32 hi] cos
    float* st1 = ct1 + 512 * 32;
    float* ct2 = st1 + 512 * 32;          // [512 f][64 lo] cos
    float* st2 = ct2 + 512 * 64;

    const dim3 blk(256);

    // fp32 -> bf16 conversions + RoPE table fill: 1 dispatch
    cvt_all<<<dim3(6240), blk, 0, stream>>>(x, wq, wk, wv, wo, xb, wqb,
                                            ct1, st1, ct2, st2);

    // QKV fused: z in {0,1,2} -> q, k, v   (M=8192, N=1024, K=1024)
    gemm_bt<u16><<<dim3(8, 64, 3), blk, 0, stream>>>(xb, wqb, q,
        1024, 1024, 1024, 1024, 0, M1, 8 * M1, 1.0f);

    // UT (512 blocks, launched first) + table-driven RoPE on q,k (8192)
    rope_ut<<<dim3(512 + 8192), blk, 0, stream>>>(q, kk, ct1, st1, ct2, st2,
                                                  wob, v, UT);

    // scores = q @ k^T / 32  (M=N=2048, K=1024, z=0..3; full 1024-block grid)
    gemm_bt<u16><<<dim3(16, 16, 4), blk, 0, stream>>>(q, kk, sc,
        1024, 1024, 2048, 1024, 2 * M1, 2 * M1, 4 * M1, 0.03125f);

    softmax_kernel<<<dim3(8192), blk, 0, stream>>>(sc, sc);

    // out[b] = P[b] @ UT[b]^T   (M=2048, N=1024, K=2048), fp32 output
    gemm_bt<float><<<dim3(8, 16, 4), blk, 0, stream>>>(sc, UT, out,
        2048, 2048, 1024, 2048, 4 * M1, 2 * M1, 2 * M1, 1.0f);
}

// Round 11
// 347.933 us; speedup vs baseline: 1.0225x; 1.0225x over previous
//
#include <hip/hip_runtime.h>
#include <math.h>

typedef __attribute__((ext_vector_type(8))) short short8;
typedef __attribute__((ext_vector_type(4))) float f32x4;
typedef unsigned short u16;

__device__ __forceinline__ float b2f(u16 u) {
    union { unsigned u; float f; } c; c.u = ((unsigned)u) << 16; return c.f;
}
__device__ __forceinline__ u16 f2b(float f) {
    unsigned u = __float_as_uint(f);
    u += 0x7fffu + ((u >> 16) & 1u);   // RNE
    return (u16)(u >> 16);
}

__device__ __forceinline__ void gl_lds16(const u16* g, u16* l) {
    __builtin_amdgcn_global_load_lds(
        (const __attribute__((address_space(1))) void*)g,
        (__attribute__((address_space(3))) void*)l,
        16, 0, 0);
}

// XCD-chunked 2D block swizzle (T1): work id = (l%8)*(nxy/8) + l/8 gives
// each XCD a contiguous chunk of (x,y) tiles. Verified R9: dual FETCH
// 135.7 -> 90.3 MB. R8 lesson: never combine with a logical-coordinate
// early-exit (concentrates exits onto a subset of XCDs).
__device__ __forceinline__ void xcd_swz(int& bx, int& by) {
    const int nxy = gridDim.x * gridDim.y;
    const int l = blockIdx.x + gridDim.x * blockIdx.y;
    const int l2 = (l & 7) * (nxy >> 3) + (l >> 3);
    bx = l2 % gridDim.x;
    by = l2 / gridDim.x;
}

// fused fp32 -> bf16 conversion: x (blocks 0..4095) + 4 weight matrices
// (blocks 4096..6143) + two-level RoPE tables (blocks 6144..6239).
// ang(pos,f) = hi*64*th_f + lo*th_f; T1[512][32] + T2[512][64] = 384 KB,
// L2-resident (R6 lesson: 8 MB table thrashes the 4 MB per-XCD L2).
// All trig lives HERE (R5 lesson: libm in a GEMM epilogue spills).
// Composition verified R7/R10 (absmax identical to direct sincosf).
__global__ __launch_bounds__(256) void cvt_all(
    const float* __restrict__ x,
    const float* __restrict__ w0, const float* __restrict__ w1,
    const float* __restrict__ w2, const float* __restrict__ w3,
    u16* __restrict__ xb, u16* __restrict__ wb,
    float* __restrict__ ct1, float* __restrict__ st1,
    float* __restrict__ ct2, float* __restrict__ st2)
{
    const int b = blockIdx.x;
    if (b >= 6144) {
        const int j = b - 6144;            // 0..95
#pragma unroll
        for (int it = 0; it < 2; ++it) {
            const int f = threadIdx.x + it * 256;   // 0..511
            const float inv = powf(10000.0f, -(float)f * (1.0f / 512.0f));
            float sn, cs;
            if (j < 32) {                  // T1: pos_hi = j
                sincosf((float)(j * 64) * inv, &sn, &cs);
                ct1[f * 32 + j] = cs;
                st1[f * 32 + j] = sn;
            } else {                       // T2: pos_lo = j-32
                const int lo = j - 32;
                sincosf((float)lo * inv, &sn, &cs);
                ct2[f * 64 + lo] = cs;
                st2[f * 64 + lo] = sn;
            }
        }
        return;
    }
    const float* src; u16* dst; int i;
    if (b < 4096) {
        i = (b * 256 + threadIdx.x) * 8;
        src = x; dst = xb;
    } else {
        const int j = b - 4096;
        const int z = j >> 9;
        src = (z == 0) ? w0 : (z == 1) ? w1 : (z == 2) ? w2 : w3;
        i = ((j & 511) * 256 + threadIdx.x) * 8;
        dst = wb + (long)z * 1024 * 1024;
    }
    const float4 a = *(const float4*)&src[i];
    const float4 c = *(const float4*)&src[i + 4];
    short8 o;
    o[0] = (short)f2b(a.x); o[1] = (short)f2b(a.y);
    o[2] = (short)f2b(a.z); o[3] = (short)f2b(a.w);
    o[4] = (short)f2b(c.x); o[5] = (short)f2b(c.y);
    o[6] = (short)f2b(c.z); o[7] = (short)f2b(c.w);
    *(short8*)&dst[i] = o;
}

// Shared 128x128-tile GEMM body: C[M,N] = scale * A[M,K] @ W[N,K]^T
// bf16 in, fp32 accum. XOR-swizzled LDS (0 conflicts); loop-carried
// pointers; double-buffered glds K-loop, ONE barrier per step.
// R0-proven structure (697 TF here — best of 5 schedule variants R1-R4).
template<typename OT>
__device__ __forceinline__ void gemm_body(
    const u16* __restrict__ A, const u16* __restrict__ W, OT* __restrict__ C,
    int lda, int ldw, int ldc, int K, float scale, int bx, int by)
{
    __shared__ u16 lsA[2][128 * 32];
    __shared__ u16 lsB[2][128 * 32];

    const int m0 = by * 128;
    const int n0 = bx * 128;
    const int t = threadIdx.x;
    const int lane = t & 63;
    const int wave = t >> 6;
    const int wm = (wave & 1) * 64;
    const int wn = (wave >> 1) * 64;

    const int sr = t >> 2;
    const int scol = ((t & 3) ^ ((t >> 3) & 3)) * 8;

    const u16* pa0 = A + (long)(m0 + sr) * lda + scol;
    const u16* pa1 = pa0 + (long)64 * lda;
    const u16* pw0 = W + (long)(n0 + sr) * ldw + scol;
    const u16* pw1 = pw0 + (long)64 * ldw;

    f32x4 acc[4][4];
#pragma unroll
    for (int i = 0; i < 4; ++i)
#pragma unroll
        for (int j = 0; j < 4; ++j)
            acc[i][j] = (f32x4){0.f, 0.f, 0.f, 0.f};

    const int fr = lane & 15;   // fragment row (m / n)
    const int fq = lane >> 4;   // quad
    const int swz = (fq ^ ((fr >> 1) & 3)) * 8;
    const int aoff = (wm + fr) * 32 + swz;
    const int boff = (wn + fr) * 32 + swz;

    gl_lds16(pa0, &lsA[0][t * 8]);        pa0 += 32;
    gl_lds16(pa1, &lsA[0][2048 + t * 8]); pa1 += 32;
    gl_lds16(pw0, &lsB[0][t * 8]);        pw0 += 32;
    gl_lds16(pw1, &lsB[0][2048 + t * 8]); pw1 += 32;

    const int nsteps = K >> 5;
    int par = 0;
    for (int s = 0; s < nsteps; ++s) {
        __syncthreads();   // drains vmcnt: buf[par] ready; prior ds_reads done
        if (s + 1 < nsteps) {
            const int np = par ^ 1;
            gl_lds16(pa0, &lsA[np][t * 8]);        pa0 += 32;
            gl_lds16(pa1, &lsA[np][2048 + t * 8]); pa1 += 32;
            gl_lds16(pw0, &lsB[np][t * 8]);        pw0 += 32;
            gl_lds16(pw1, &lsB[np][2048 + t * 8]); pw1 += 32;
        }

        short8 af[4], bf[4];
#pragma unroll
        for (int i = 0; i < 4; ++i)
            af[i] = *(const short8*)&lsA[par][aoff + i * 512];
#pragma unroll
        for (int j = 0; j < 4; ++j)
            bf[j] = *(const short8*)&lsB[par][boff + j * 512];
#pragma unroll
        for (int i = 0; i < 4; ++i)
#pragma unroll
            for (int j = 0; j < 4; ++j)
                acc[i][j] = __builtin_amdgcn_mfma_f32_16x16x32_bf16(af[i], bf[j], acc[i][j], 0, 0, 0);
        par ^= 1;
    }

    // C/D layout: col = lane&15, row = quad*4 + reg  [verified m89/m91]
#pragma unroll
    for (int i = 0; i < 4; ++i) {
#pragma unroll
        for (int j = 0; j < 4; ++j) {
            const int row0 = m0 + wm + i * 16 + fq * 4;
            const int col = n0 + wn + j * 16 + fr;
#pragma unroll
            for (int r = 0; r < 4; ++r) {
                const int row = row0 + r;
                const float val = acc[i][j][r] * scale;
                if (sizeof(OT) == 2) {
                    ((u16*)C)[(long)row * ldc + col] = f2b(val);
                } else {
                    ((float*)C)[(long)row * ldc + col] = val;
                }
            }
        }
    }
}

// generic z-strided GEMM (XCD-swizzled tiles; no early exits here)
template<typename OT>
__global__ __launch_bounds__(256) void gemm_bt(
    const u16* __restrict__ A, const u16* __restrict__ W, OT* __restrict__ C,
    int lda, int ldw, int ldc, int K,
    long sA, long sW, long sC, float scale)
{
    int bx, by;
    xcd_swz(bx, by);
    const int bz = blockIdx.z;
    gemm_body<OT>(A + (long)bz * sA, W + (long)bz * sW, C + (long)bz * sC,
                  lda, ldw, ldc, K, scale, bx, by);
}

// dual GEMM (R9-proven, 72.1 us): z<4 -> scores batch z (full grid,
// swizzled); z>=4 -> UT batch z-4 with y<8 early-exit on RAW blockIdx
// (exiting blocks round-robin evenly across XCDs).
// R10 lesson: do NOT move UT into a streaming-kernel dispatch — GEMM
// blocks starve next to thousands of short memory-bound blocks.
__global__ __launch_bounds__(256) void gemm_dual(
    const u16* __restrict__ A0, const u16* __restrict__ W0, u16* __restrict__ C0,
    int lda0, int ldw0, int ldc0, long sA0, long sW0, long sC0, float scale0,
    const u16* __restrict__ A1, const u16* __restrict__ W1, u16* __restrict__ C1,
    int lda1, int ldw1, int ldc1, long sA1, long sW1, long sC1, float scale1)
{
    const int z = blockIdx.z;
    if (z < 4) {
        int bx, by;
        xcd_swz(bx, by);
        gemm_body<u16>(A0 + (long)z * sA0, W0 + (long)z * sW0, C0 + (long)z * sC0,
                       lda0, ldw0, ldc0, 1024, scale0, bx, by);
    } else {
        if (blockIdx.y >= 8) return;   // uniform early-exit, before any barrier
        const int b = z - 4;
        gemm_body<u16>(A1 + (long)b * sA1, W1 + (long)b * sW1, C1 + (long)b * sC1,
                       lda1, ldw1, ldc1, 1024, scale1, blockIdx.x, blockIdx.y);
    }
}

// standalone table-driven RoPE on q AND k: one block per row; no libm
// (8 L2-resident table loads + 12 FMA per thread), ushort4 accesses.
// Math verified R7/R10 (absmax identical to sincosf version).
__global__ __launch_bounds__(256) void rope_tab(
    u16* __restrict__ q, u16* __restrict__ k,
    const float* __restrict__ ct1, const float* __restrict__ st1,
    const float* __restrict__ ct2, const float* __restrict__ st2)
{
    const int row = blockIdx.x;        // 0..8191
    const int pos = row & 2047;
    const int hi = pos >> 6;
    const int lo = pos & 63;
    const int t = threadIdx.x;
    const int f0 = 2 * t;              // pairs f0, f0+1 -> elems 4t..4t+3

    const float c1a = ct1[f0 * 32 + hi],       s1a = st1[f0 * 32 + hi];
    const float c2a = ct2[f0 * 64 + lo],       s2a = st2[f0 * 64 + lo];
    const float c1b = ct1[(f0 + 1) * 32 + hi], s1b = st1[(f0 + 1) * 32 + hi];
    const float c2b = ct2[(f0 + 1) * 64 + lo], s2b = st2[(f0 + 1) * 64 + lo];
    const float ca = c1a * c2a - s1a * s2a, sa = s1a * c2a + c1a * s2a;
    const float cb = c1b * c2b - s1b * s2b, sb = s1b * c2b + c1b * s2b;

    u16* pq = q + (long)row * 1024 + 4 * t;
    u16* pk = k + (long)row * 1024 + 4 * t;

    ushort4 vq = *(ushort4*)pq;
    {
        const float xr0 = b2f(vq.x), xi0 = b2f(vq.y);
        const float xr1 = b2f(vq.z), xi1 = b2f(vq.w);
        vq.x = f2b(xr0 * ca - xi0 * sa); vq.y = f2b(xr0 * sa + xi0 * ca);
        vq.z = f2b(xr1 * cb - xi1 * sb); vq.w = f2b(xr1 * sb + xi1 * cb);
    }
    *(ushort4*)pq = vq;

    ushort4 vk = *(ushort4*)pk;
    {
        const float xr0 = b2f(vk.x), xi0 = b2f(vk.y);
        const float xr1 = b2f(vk.z), xi1 = b2f(vk.w);
        vk.x = f2b(xr0 * ca - xi0 * sa); vk.y = f2b(xr0 * sa + xi0 * ca);
        vk.z = f2b(xr1 * cb - xi1 * sb); vk.w = f2b(xr1 * sb + xi1 * cb);
    }
    *(ushort4*)pk = vk;
}

// row-wise softmax over 2048 bf16 entries, in-place safe; one block per row
__global__ __launch_bounds__(256) void softmax_kernel(const u16* __restrict__ S, u16* __restrict__ P) {
    const long row = blockIdx.x;
    const u16* src = S + row * 2048;
    u16* dst = P + row * 2048;
    const int t = threadIdx.x;
    const int lane = t & 63;
    const int wave = t >> 6;
    __shared__ float red[4];

    float v[8];
    const short8 raw = *(const short8*)&src[t * 8];
#pragma unroll
    for (int i = 0; i < 8; ++i) v[i] = b2f((u16)raw[i]);

    float m = v[0];
#pragma unroll
    for (int i = 1; i < 8; ++i) m = fmaxf(m, v[i]);
    for (int o = 32; o > 0; o >>= 1) m = fmaxf(m, __shfl_xor(m, o, 64));
    if (lane == 0) red[wave] = m;
    __syncthreads();
    m = fmaxf(fmaxf(red[0], red[1]), fmaxf(red[2], red[3]));
    __syncthreads();

    float sum = 0.f;
#pragma unroll
    for (int i = 0; i < 8; ++i) { v[i] = expf(v[i] - m); sum += v[i]; }
    for (int o = 32; o > 0; o >>= 1) sum += __shfl_xor(sum, o, 64);
    if (lane == 0) red[wave] = sum;
    __syncthreads();
    sum = red[0] + red[1] + red[2] + red[3];
    const float is = 1.0f / sum;

    short8 outv;
#pragma unroll
    for (int i = 0; i < 8; ++i) outv[i] = (short)f2b(v[i] * is);
    *(short8*)&dst[t * 8] = outv;
}

extern "C" void kernel_launch(void* const* d_in, const int* in_sizes, int n_in,
                              void* d_out, int out_size, void* d_ws, size_t ws_size,
                              hipStream_t stream)
{
    (void)in_sizes; (void)n_in; (void)out_size; (void)ws_size;
    const float* x  = (const float*)d_in[0];
    const float* wq = (const float*)d_in[1];
    const float* wk = (const float*)d_in[2];
    const float* wv = (const float*)d_in[3];
    const float* wo = (const float*)d_in[4];
    float* out = (float*)d_out;

    // workspace layout (bf16 elements), 104 MB + 384 KB tables
    const long M1 = 1024 * 1024;
    u16* ws  = (u16*)d_ws;
    u16* xb  = ws;               // [8192][1024] bf16 x; reused as UT after QKV
    u16* wqb = xb + 8 * M1;      // [4][1024][1024] wq,wk,wv,wo contiguous
    u16* wob = wqb + 3 * M1;
    u16* q   = wqb + 4 * M1;     // [8192][1024]; kk, v contiguous after (z-strided)
    u16* kk  = q + 8 * M1;
    u16* v   = kk + 8 * M1;
    u16* sc  = v + 8 * M1;       // [4][2048][2048], softmax in-place
    u16* UT  = xb;               // alias: [4][1024][2048], xb dead after QKV
    float* ct1 = (float*)(sc + 16 * M1);  // [512 f][32 hi] cos
    float* st1 = ct1 + 512 * 32;
    float* ct2 = st1 + 512 * 32;          // [512 f][64 lo] cos
    float* st2 = ct2 + 512 * 64;

    const dim3 blk(256);

    // fp32 -> bf16 conversions + RoPE table fill: 1 dispatch
    cvt_all<<<dim3(6240), blk, 0, stream>>>(x, wq, wk, wv, wo, xb, wqb,
                                            ct1, st1, ct2, st2);

    // QKV fused: z in {0,1,2} -> q, k, v   (M=8192, N=1024, K=1024)
    gemm_bt<u16><<<dim3(8, 64, 3), blk, 0, stream>>>(xb, wqb, q,
        1024, 1024, 1024, 1024, 0, M1, 8 * M1, 1.0f);

    // table-driven RoPE on q,k (standalone — R10: never co-dispatch with GEMM)
    rope_tab<<<dim3(8192), blk, 0, stream>>>(q, kk, ct1, st1, ct2, st2);

    // fused: scores = q @ k^T / 32 (M=N=2048,K=1024, z=0..3)
    //      + UT[b][e][k] = wo @ v[b]^T (M=1024,N=2048,K=1024, z=4..7, y<8)
    gemm_dual<<<dim3(16, 16, 8), blk, 0, stream>>>(
        q, kk, sc, 1024, 1024, 2048, 2 * M1, 2 * M1, 4 * M1, 0.03125f,
        wob, v, UT, 1024, 1024, 2048, 0, 2 * M1, 2 * M1, 1.0f);

    softmax_kernel<<<dim3(8192), blk, 0, stream>>>(sc, sc);

    // out[b] = P[b] @ UT[b]^T   (M=2048, N=1024, K=2048), fp32 output
    gemm_bt<float><<<dim3(8, 16, 4), blk, 0, stream>>>(sc, UT, out,
        2048, 2048, 1024, 2048, 4 * M1, 2 * M1, 2 * M1, 1.0f);
}

// Round 12
// 299.707 us; speedup vs baseline: 1.1870x; 1.1609x over previous
//
#include <hip/hip_runtime.h>
#include <math.h>

typedef __attribute__((ext_vector_type(8))) short short8;
typedef __attribute__((ext_vector_type(4))) float f32x4;
typedef unsigned short u16;

__device__ __forceinline__ float b2f(u16 u) {
    union { unsigned u; float f; } c; c.u = ((unsigned)u) << 16; return c.f;
}
__device__ __forceinline__ u16 f2b(float f) {
    unsigned u = __float_as_uint(f);
    u += 0x7fffu + ((u >> 16) & 1u);   // RNE
    return (u16)(u >> 16);
}

__device__ __forceinline__ void gl_lds16(const u16* g, u16* l) {
    __builtin_amdgcn_global_load_lds(
        (const __attribute__((address_space(1))) void*)g,
        (__attribute__((address_space(3))) void*)l,
        16, 0, 0);
}

// XCD-chunked 2D block swizzle (T1): work id = (l%8)*(nxy/8) + l/8 gives
// each XCD a contiguous chunk of (x,y) tiles. Verified R9: dual FETCH
// 135.7 -> 90.3 MB. R8 lesson: never combine with a logical-coordinate
// early-exit (concentrates exits onto a subset of XCDs).
__device__ __forceinline__ void xcd_swz(int& bx, int& by) {
    const int nxy = gridDim.x * gridDim.y;
    const int l = blockIdx.x + gridDim.x * blockIdx.y;
    const int l2 = (l & 7) * (nxy >> 3) + (l >> 3);
    bx = l2 % gridDim.x;
    by = l2 / gridDim.x;
}

// fused fp32 -> bf16 conversion: x (blocks 0..4095) + 4 weight matrices
// (blocks 4096..6143) + two-level RoPE tables (blocks 6144..6239).
// ang(pos,f) = hi*64*th_f + lo*th_f; tables TRANSPOSED to [pos][f]:
// T1[32 hi][512 f] + T2[64 lo][512 f] = 384 KB, L2-resident.
// R11 lesson: the [f][pos] layout made the rope kernel gather-bound
// (lane stride 256 B, 74 us at 3.8% VALUBusy); [pos][f] is coalesced
// because pos is block-uniform and f is the lane axis.
// All trig lives HERE (R5 lesson: libm in a GEMM epilogue spills).
// Composition verified R7/R10/R11 (absmax identical to direct sincosf).
__global__ __launch_bounds__(256) void cvt_all(
    const float* __restrict__ x,
    const float* __restrict__ w0, const float* __restrict__ w1,
    const float* __restrict__ w2, const float* __restrict__ w3,
    u16* __restrict__ xb, u16* __restrict__ wb,
    float* __restrict__ ct1, float* __restrict__ st1,
    float* __restrict__ ct2, float* __restrict__ st2)
{
    const int b = blockIdx.x;
    if (b >= 6144) {
        const int j = b - 6144;            // 0..95
#pragma unroll
        for (int it = 0; it < 2; ++it) {
            const int f = threadIdx.x + it * 256;   // 0..511
            const float inv = powf(10000.0f, -(float)f * (1.0f / 512.0f));
            float sn, cs;
            if (j < 32) {                  // T1 row hi=j: angle = j*64*th_f
                sincosf((float)(j * 64) * inv, &sn, &cs);
                ct1[j * 512 + f] = cs;
                st1[j * 512 + f] = sn;
            } else {                       // T2 row lo=j-32: angle = lo*th_f
                const int lo = j - 32;
                sincosf((float)lo * inv, &sn, &cs);
                ct2[lo * 512 + f] = cs;
                st2[lo * 512 + f] = sn;
            }
        }
        return;
    }
    const float* src; u16* dst; int i;
    if (b < 4096) {
        i = (b * 256 + threadIdx.x) * 8;
        src = x; dst = xb;
    } else {
        const int j = b - 4096;
        const int z = j >> 9;
        src = (z == 0) ? w0 : (z == 1) ? w1 : (z == 2) ? w2 : w3;
        i = ((j & 511) * 256 + threadIdx.x) * 8;
        dst = wb + (long)z * 1024 * 1024;
    }
    const float4 a = *(const float4*)&src[i];
    const float4 c = *(const float4*)&src[i + 4];
    short8 o;
    o[0] = (short)f2b(a.x); o[1] = (short)f2b(a.y);
    o[2] = (short)f2b(a.z); o[3] = (short)f2b(a.w);
    o[4] = (short)f2b(c.x); o[5] = (short)f2b(c.y);
    o[6] = (short)f2b(c.z); o[7] = (short)f2b(c.w);
    *(short8*)&dst[i] = o;
}

// Shared 128x128-tile GEMM body: C[M,N] = scale * A[M,K] @ W[N,K]^T
// bf16 in, fp32 accum. XOR-swizzled LDS (0 conflicts); loop-carried
// pointers; double-buffered glds K-loop, ONE barrier per step.
// R0-proven structure (697 TF here — best of 5 schedule variants R1-R4).
template<typename OT>
__device__ __forceinline__ void gemm_body(
    const u16* __restrict__ A, const u16* __restrict__ W, OT* __restrict__ C,
    int lda, int ldw, int ldc, int K, float scale, int bx, int by)
{
    __shared__ u16 lsA[2][128 * 32];
    __shared__ u16 lsB[2][128 * 32];

    const int m0 = by * 128;
    const int n0 = bx * 128;
    const int t = threadIdx.x;
    const int lane = t & 63;
    const int wave = t >> 6;
    const int wm = (wave & 1) * 64;
    const int wn = (wave >> 1) * 64;

    const int sr = t >> 2;
    const int scol = ((t & 3) ^ ((t >> 3) & 3)) * 8;

    const u16* pa0 = A + (long)(m0 + sr) * lda + scol;
    const u16* pa1 = pa0 + (long)64 * lda;
    const u16* pw0 = W + (long)(n0 + sr) * ldw + scol;
    const u16* pw1 = pw0 + (long)64 * ldw;

    f32x4 acc[4][4];
#pragma unroll
    for (int i = 0; i < 4; ++i)
#pragma unroll
        for (int j = 0; j < 4; ++j)
            acc[i][j] = (f32x4){0.f, 0.f, 0.f, 0.f};

    const int fr = lane & 15;   // fragment row (m / n)
    const int fq = lane >> 4;   // quad
    const int swz = (fq ^ ((fr >> 1) & 3)) * 8;
    const int aoff = (wm + fr) * 32 + swz;
    const int boff = (wn + fr) * 32 + swz;

    gl_lds16(pa0, &lsA[0][t * 8]);        pa0 += 32;
    gl_lds16(pa1, &lsA[0][2048 + t * 8]); pa1 += 32;
    gl_lds16(pw0, &lsB[0][t * 8]);        pw0 += 32;
    gl_lds16(pw1, &lsB[0][2048 + t * 8]); pw1 += 32;

    const int nsteps = K >> 5;
    int par = 0;
    for (int s = 0; s < nsteps; ++s) {
        __syncthreads();   // drains vmcnt: buf[par] ready; prior ds_reads done
        if (s + 1 < nsteps) {
            const int np = par ^ 1;
            gl_lds16(pa0, &lsA[np][t * 8]);        pa0 += 32;
            gl_lds16(pa1, &lsA[np][2048 + t * 8]); pa1 += 32;
            gl_lds16(pw0, &lsB[np][t * 8]);        pw0 += 32;
            gl_lds16(pw1, &lsB[np][2048 + t * 8]); pw1 += 32;
        }

        short8 af[4], bf[4];
#pragma unroll
        for (int i = 0; i < 4; ++i)
            af[i] = *(const short8*)&lsA[par][aoff + i * 512];
#pragma unroll
        for (int j = 0; j < 4; ++j)
            bf[j] = *(const short8*)&lsB[par][boff + j * 512];
#pragma unroll
        for (int i = 0; i < 4; ++i)
#pragma unroll
            for (int j = 0; j < 4; ++j)
                acc[i][j] = __builtin_amdgcn_mfma_f32_16x16x32_bf16(af[i], bf[j], acc[i][j], 0, 0, 0);
        par ^= 1;
    }

    // C/D layout: col = lane&15, row = quad*4 + reg  [verified m89/m91]
#pragma unroll
    for (int i = 0; i < 4; ++i) {
#pragma unroll
        for (int j = 0; j < 4; ++j) {
            const int row0 = m0 + wm + i * 16 + fq * 4;
            const int col = n0 + wn + j * 16 + fr;
#pragma unroll
            for (int r = 0; r < 4; ++r) {
                const int row = row0 + r;
                const float val = acc[i][j][r] * scale;
                if (sizeof(OT) == 2) {
                    ((u16*)C)[(long)row * ldc + col] = f2b(val);
                } else {
                    ((float*)C)[(long)row * ldc + col] = val;
                }
            }
        }
    }
}

// generic z-strided GEMM (XCD-swizzled tiles; no early exits here)
template<typename OT>
__global__ __launch_bounds__(256) void gemm_bt(
    const u16* __restrict__ A, const u16* __restrict__ W, OT* __restrict__ C,
    int lda, int ldw, int ldc, int K,
    long sA, long sW, long sC, float scale)
{
    int bx, by;
    xcd_swz(bx, by);
    const int bz = blockIdx.z;
    gemm_body<OT>(A + (long)bz * sA, W + (long)bz * sW, C + (long)bz * sC,
                  lda, ldw, ldc, K, scale, bx, by);
}

// dual GEMM (R9-proven, 72.1 us): z<4 -> scores batch z (full grid,
// swizzled); z>=4 -> UT batch z-4 with y<8 early-exit on RAW blockIdx
// (exiting blocks round-robin evenly across XCDs).
// R10 lesson: do NOT move UT into a streaming-kernel dispatch — GEMM
// blocks starve next to thousands of short memory-bound blocks.
__global__ __launch_bounds__(256) void gemm_dual(
    const u16* __restrict__ A0, const u16* __restrict__ W0, u16* __restrict__ C0,
    int lda0, int ldw0, int ldc0, long sA0, long sW0, long sC0, float scale0,
    const u16* __restrict__ A1, const u16* __restrict__ W1, u16* __restrict__ C1,
    int lda1, int ldw1, int ldc1, long sA1, long sW1, long sC1, float scale1)
{
    const int z = blockIdx.z;
    if (z < 4) {
        int bx, by;
        xcd_swz(bx, by);
        gemm_body<u16>(A0 + (long)z * sA0, W0 + (long)z * sW0, C0 + (long)z * sC0,
                       lda0, ldw0, ldc0, 1024, scale0, bx, by);
    } else {
        if (blockIdx.y >= 8) return;   // uniform early-exit, before any barrier
        const int b = z - 4;
        gemm_body<u16>(A1 + (long)b * sA1, W1 + (long)b * sW1, C1 + (long)b * sC1,
                       lda1, ldw1, ldc1, 1024, scale1, blockIdx.x, blockIdx.y);
    }
}

// standalone table-driven RoPE on q AND k: one block per row; no libm.
// [pos][f] table layout: pos (hi/lo) is block-uniform, f = lane axis ->
// float2 loads, consecutive lanes consecutive addresses (coalesced; the
// 2 KB rows L1-cache after the first wave). R11 lesson fixed.
__global__ __launch_bounds__(256) void rope_tab(
    u16* __restrict__ q, u16* __restrict__ k,
    const float* __restrict__ ct1, const float* __restrict__ st1,
    const float* __restrict__ ct2, const float* __restrict__ st2)
{
    const int row = blockIdx.x;        // 0..8191
    const int pos = row & 2047;
    const int hi = pos >> 6;
    const int lo = pos & 63;
    const int t = threadIdx.x;
    const int f0 = 2 * t;              // pairs f0, f0+1 -> elems 4t..4t+3

    const float2 c1 = *(const float2*)&ct1[hi * 512 + f0];
    const float2 s1 = *(const float2*)&st1[hi * 512 + f0];
    const float2 c2 = *(const float2*)&ct2[lo * 512 + f0];
    const float2 s2 = *(const float2*)&st2[lo * 512 + f0];
    const float ca = c1.x * c2.x - s1.x * s2.x, sa = s1.x * c2.x + c1.x * s2.x;
    const float cb = c1.y * c2.y - s1.y * s2.y, sb = s1.y * c2.y + c1.y * s2.y;

    u16* pq = q + (long)row * 1024 + 4 * t;
    u16* pk = k + (long)row * 1024 + 4 * t;

    ushort4 vq = *(ushort4*)pq;
    {
        const float xr0 = b2f(vq.x), xi0 = b2f(vq.y);
        const float xr1 = b2f(vq.z), xi1 = b2f(vq.w);
        vq.x = f2b(xr0 * ca - xi0 * sa); vq.y = f2b(xr0 * sa + xi0 * ca);
        vq.z = f2b(xr1 * cb - xi1 * sb); vq.w = f2b(xr1 * sb + xi1 * cb);
    }
    *(ushort4*)pq = vq;

    ushort4 vk = *(ushort4*)pk;
    {
        const float xr0 = b2f(vk.x), xi0 = b2f(vk.y);
        const float xr1 = b2f(vk.z), xi1 = b2f(vk.w);
        vk.x = f2b(xr0 * ca - xi0 * sa); vk.y = f2b(xr0 * sa + xi0 * ca);
        vk.z = f2b(xr1 * cb - xi1 * sb); vk.w = f2b(xr1 * sb + xi1 * cb);
    }
    *(ushort4*)pk = vk;
}

// row-wise softmax over 2048 bf16 entries, in-place safe; one block per row
__global__ __launch_bounds__(256) void softmax_kernel(const u16* __restrict__ S, u16* __restrict__ P) {
    const long row = blockIdx.x;
    const u16* src = S + row * 2048;
    u16* dst = P + row * 2048;
    const int t = threadIdx.x;
    const int lane = t & 63;
    const int wave = t >> 6;
    __shared__ float red[4];

    float v[8];
    const short8 raw = *(const short8*)&src[t * 8];
#pragma unroll
    for (int i = 0; i < 8; ++i) v[i] = b2f((u16)raw[i]);

    float m = v[0];
#pragma unroll
    for (int i = 1; i < 8; ++i) m = fmaxf(m, v[i]);
    for (int o = 32; o > 0; o >>= 1) m = fmaxf(m, __shfl_xor(m, o, 64));
    if (lane == 0) red[wave] = m;
    __syncthreads();
    m = fmaxf(fmaxf(red[0], red[1]), fmaxf(red[2], red[3]));
    __syncthreads();

    float sum = 0.f;
#pragma unroll
    for (int i = 0; i < 8; ++i) { v[i] = expf(v[i] - m); sum += v[i]; }
    for (int o = 32; o > 0; o >>= 1) sum += __shfl_xor(sum, o, 64);
    if (lane == 0) red[wave] = sum;
    __syncthreads();
    sum = red[0] + red[1] + red[2] + red[3];
    const float is = 1.0f / sum;

    short8 outv;
#pragma unroll
    for (int i = 0; i < 8; ++i) outv[i] = (short)f2b(v[i] * is);
    *(short8*)&dst[t * 8] = outv;
}

extern "C" void kernel_launch(void* const* d_in, const int* in_sizes, int n_in,
                              void* d_out, int out_size, void* d_ws, size_t ws_size,
                              hipStream_t stream)
{
    (void)in_sizes; (void)n_in; (void)out_size; (void)ws_size;
    const float* x  = (const float*)d_in[0];
    const float* wq = (const float*)d_in[1];
    const float* wk = (const float*)d_in[2];
    const float* wv = (const float*)d_in[3];
    const float* wo = (const float*)d_in[4];
    float* out = (float*)d_out;

    // workspace layout (bf16 elements), 104 MB + 384 KB tables
    const long M1 = 1024 * 1024;
    u16* ws  = (u16*)d_ws;
    u16* xb  = ws;               // [8192][1024] bf16 x; reused as UT after QKV
    u16* wqb = xb + 8 * M1;      // [4][1024][1024] wq,wk,wv,wo contiguous
    u16* wob = wqb + 3 * M1;
    u16* q   = wqb + 4 * M1;     // [8192][1024]; kk, v contiguous after (z-strided)
    u16* kk  = q + 8 * M1;
    u16* v   = kk + 8 * M1;
    u16* sc  = v + 8 * M1;       // [4][2048][2048], softmax in-place
    u16* UT  = xb;               // alias: [4][1024][2048], xb dead after QKV
    float* ct1 = (float*)(sc + 16 * M1);  // [32 hi][512 f] cos
    float* st1 = ct1 + 32 * 512;
    float* ct2 = st1 + 32 * 512;          // [64 lo][512 f] cos
    float* st2 = ct2 + 64 * 512;

    const dim3 blk(256);

    // fp32 -> bf16 conversions + RoPE table fill: 1 dispatch
    cvt_all<<<dim3(6240), blk, 0, stream>>>(x, wq, wk, wv, wo, xb, wqb,
                                            ct1, st1, ct2, st2);

    // QKV fused: z in {0,1,2} -> q, k, v   (M=8192, N=1024, K=1024)
    gemm_bt<u16><<<dim3(8, 64, 3), blk, 0, stream>>>(xb, wqb, q,
        1024, 1024, 1024, 1024, 0, M1, 8 * M1, 1.0f);

    // table-driven RoPE on q,k (standalone — R10: never co-dispatch with GEMM)
    rope_tab<<<dim3(8192), blk, 0, stream>>>(q, kk, ct1, st1, ct2, st2);

    // fused: scores = q @ k^T / 32 (M=N=2048,K=1024, z=0..3)
    //      + UT[b][e][k] = wo @ v[b]^T (M=1024,N=2048,K=1024, z=4..7, y<8)
    gemm_dual<<<dim3(16, 16, 8), blk, 0, stream>>>(
        q, kk, sc, 1024, 1024, 2048, 2 * M1, 2 * M1, 4 * M1, 0.03125f,
        wob, v, UT, 1024, 1024, 2048, 0, 2 * M1, 2 * M1, 1.0f);

    softmax_kernel<<<dim3(8192), blk, 0, stream>>>(sc, sc);

    // out[b] = P[b] @ UT[b]^T   (M=2048, N=1024, K=2048), fp32 output
    gemm_bt<float><<<dim3(8, 16, 4), blk, 0, stream>>>(sc, UT, out,
        2048, 2048, 1024, 2048, 4 * M1, 2 * M1, 2 * M1, 1.0f);
}